// Round 1
// baseline (185.403 us; speedup 1.0000x reference)
//
#include <hip/hip_runtime.h>
#include <hip/hip_bf16.h>
#include <stdint.h>

// B=4, T=1024, C=1024, H=16, D=64
// ws layout (bf16 elems): xb[4096*1024] | wqkvT[3072*1024] | woT[1024*1024]
//                       | q[4M] | k[4M] | v[4M] | O[4M]   => 48 MB total

typedef float f32x4 __attribute__((ext_vector_type(4)));
typedef __bf16 bf16x8 __attribute__((ext_vector_type(8)));
typedef __bf16 bf16x4 __attribute__((ext_vector_type(4)));

#define GAS __attribute__((address_space(1)))
#define LAS __attribute__((address_space(3)))

// ---------------------------------------------------------------- cast x -> bf16
__global__ __launch_bounds__(256) void cast_bf16_kernel(
    const float* __restrict__ in, __bf16* __restrict__ out, int n4) {
  int i = blockIdx.x * 256 + threadIdx.x;
  if (i < n4) {
    float4 f = ((const float4*)in)[i];
    bf16x4 o;
    o[0] = (__bf16)f.x; o[1] = (__bf16)f.y; o[2] = (__bf16)f.z; o[3] = (__bf16)f.w;
    ((bf16x4*)out)[i] = o;
  }
}

// ------------------------------------------- transpose f32 [rows x cols] -> bf16 [cols x rows]
__global__ __launch_bounds__(256) void transpose_cast_kernel(
    const float* __restrict__ src, __bf16* __restrict__ dst,
    int src_ld, int dst_ld, long long src_mstride, long long dst_mstride) {
  __shared__ float tile[64][65];
  const float* s = src + (size_t)blockIdx.z * src_mstride;
  __bf16* d = dst + (size_t)blockIdx.z * dst_mstride;
  int r0 = blockIdx.x * 64, c0 = blockIdx.y * 64;
  int tx = threadIdx.x & 63, ty = threadIdx.x >> 6;
#pragma unroll
  for (int rr = ty; rr < 64; rr += 4)
    tile[rr][tx] = s[(size_t)(r0 + rr) * src_ld + (c0 + tx)];
  __syncthreads();
#pragma unroll
  for (int rr = ty; rr < 64; rr += 4)
    d[(size_t)(c0 + rr) * dst_ld + (r0 + tx)] = (__bf16)tile[tx][rr];
}

// ---------------------------------------------------------------- GEMM (A row-major, BT = B^T row-major)
// 128x128 tile, BK=32, 256 threads (4 waves 2x2, each 64x64), m97 structure.
// MODE 0: scatter-write q (pre-scaled 1/8), k, v as bf16 [B,H,T,D]
// MODE 1: fp32 out + bias
template <int MODE>
__global__ __launch_bounds__(256) void gemm_bt_kernel(
    const __bf16* __restrict__ A, const __bf16* __restrict__ BT, int N,
    __bf16* __restrict__ qo, __bf16* __restrict__ ko, __bf16* __restrict__ vo,
    float* __restrict__ Cout, const float* __restrict__ bias) {
  constexpr int K = 1024;
  __shared__ __align__(16) __bf16 Ash[128 * 32];
  __shared__ __align__(16) __bf16 Bsh[128 * 32];
  const int tid = threadIdx.x;
  const int wid = tid >> 6, lane = tid & 63;
  const int fr = lane & 15, fq = lane >> 4;
  const int m0 = blockIdx.x * 128, n0 = blockIdx.y * 128;
  const int wr = wid >> 1, wc = wid & 1;
  const int srow = lane >> 2, scol = (lane & 3) * 8;

  f32x4 acc[4][4] = {};

  for (int k0 = 0; k0 < K; k0 += 32) {
#pragma unroll
    for (int i = 0; i < 2; ++i) {
      int chunk = wid * 2 + i;          // 0..7, wave-uniform
      int row = chunk * 16 + srow;
      const __bf16* gA = A + (size_t)(m0 + row) * K + k0 + scol;
      const __bf16* gB = BT + (size_t)(n0 + row) * K + k0 + scol;
      __builtin_amdgcn_global_load_lds((const GAS void*)gA, (LAS void*)&Ash[chunk * 512], 16, 0, 0);
      __builtin_amdgcn_global_load_lds((const GAS void*)gB, (LAS void*)&Bsh[chunk * 512], 16, 0, 0);
    }
    __syncthreads();
    bf16x8 af[4], bfr[4];
#pragma unroll
    for (int mi = 0; mi < 4; ++mi)
      af[mi] = *(const bf16x8*)&Ash[(wr * 64 + mi * 16 + fr) * 32 + fq * 8];
#pragma unroll
    for (int ni = 0; ni < 4; ++ni)
      bfr[ni] = *(const bf16x8*)&Bsh[(wc * 64 + ni * 16 + fr) * 32 + fq * 8];
#pragma unroll
    for (int mi = 0; mi < 4; ++mi)
#pragma unroll
      for (int ni = 0; ni < 4; ++ni)
        acc[mi][ni] = __builtin_amdgcn_mfma_f32_16x16x32_bf16(af[mi], bfr[ni], acc[mi][ni], 0, 0, 0);
    __syncthreads();
  }

#pragma unroll
  for (int mi = 0; mi < 4; ++mi) {
#pragma unroll
    for (int ni = 0; ni < 4; ++ni) {
      int n = n0 + wc * 64 + ni * 16 + fr;
      int mb = m0 + wr * 64 + mi * 16 + fq * 4;
#pragma unroll
      for (int r = 0; r < 4; ++r) {
        int m = mb + r;
        float val = acc[mi][ni][r];
        if (MODE == 0) {
          int sec = n >> 10, nl = n & 1023;
          int h = nl >> 6, dd = nl & 63;
          int b = m >> 10, t = m & 1023;
          __bf16* dst = (sec == 0) ? qo : ((sec == 1) ? ko : vo);
          if (sec == 0) val *= 0.125f;  // fold 1/sqrt(D) into q
          dst[(((size_t)b * 16 + h) * 1024 + t) * 64 + dd] = (__bf16)val;
        } else {
          Cout[(size_t)m * N + n] = val + bias[n];
        }
      }
    }
  }
}

// ---------------------------------------------------------------- flash attention (causal)
// grid (T/64, B*H); 256 threads = 4 waves, wave w owns q-rows [q0+16w, q0+16w+16)
// K tile LDS [64][72] (144B rows: conflict-free b128 frag reads)
// V tile transposed into VT [64 d][72]; P per-wave [16][72]
__global__ __launch_bounds__(256) void attn_fwd_kernel(
    const __bf16* __restrict__ Q, const __bf16* __restrict__ Kg,
    const __bf16* __restrict__ Vg, __bf16* __restrict__ O) {
  __shared__ __align__(16) __bf16 Ksh[64 * 72];
  __shared__ __align__(16) __bf16 VT[64 * 72];
  __shared__ __align__(16) __bf16 Psh[4][16 * 72];
  const int qt = blockIdx.x, bh = blockIdx.y;
  const int b = bh >> 4, h = bh & 15;
  const size_t base = (size_t)bh * 1024 * 64;
  const int tid = threadIdx.x, wid = tid >> 6, lane = tid & 63;
  const int fr = lane & 15, fq = lane >> 4;
  const int q0 = qt * 64;

  bf16x8 qf[2];
  {
    int qr = q0 + wid * 16 + fr;
    qf[0] = *(const bf16x8*)&Q[base + (size_t)qr * 64 + fq * 8];
    qf[1] = *(const bf16x8*)&Q[base + (size_t)qr * 64 + 32 + fq * 8];
  }
  f32x4 oacc[4] = {};
  float mrow[4] = {-1e30f, -1e30f, -1e30f, -1e30f};
  float lrow[4] = {0.f, 0.f, 0.f, 0.f};

  for (int st = 0; st <= qt; ++st) {
    const int s0 = st * 64;
    // stage K (row-major, padded) and V (transposed, padded)
#pragma unroll
    for (int i = 0; i < 2; ++i) {
      int idx = i * 256 + tid;
      int s = idx >> 3, ch = idx & 7;
      bf16x8 kv = *(const bf16x8*)&Kg[base + (size_t)(s0 + s) * 64 + ch * 8];
      *(bf16x8*)&Ksh[s * 72 + ch * 8] = kv;
      bf16x8 vv = *(const bf16x8*)&Vg[base + (size_t)(s0 + s) * 64 + ch * 8];
#pragma unroll
      for (int j = 0; j < 8; ++j) VT[(ch * 8 + j) * 72 + s] = vv[j];
    }
    __syncthreads();

    // S = Q K^T  (q pre-scaled); rows fq*4+r, cols sf*16+fr
    f32x4 sacc[4] = {};
#pragma unroll
    for (int sf = 0; sf < 4; ++sf) {
      bf16x8 k0f = *(const bf16x8*)&Ksh[(sf * 16 + fr) * 72 + fq * 8];
      sacc[sf] = __builtin_amdgcn_mfma_f32_16x16x32_bf16(qf[0], k0f, sacc[sf], 0, 0, 0);
      bf16x8 k1f = *(const bf16x8*)&Ksh[(sf * 16 + fr) * 72 + 32 + fq * 8];
      sacc[sf] = __builtin_amdgcn_mfma_f32_16x16x32_bf16(qf[1], k1f, sacc[sf], 0, 0, 0);
    }

    // mask + online softmax (16-lane-group shfl reduces)
    const bool diag = (st == qt);
    const int qrb = q0 + wid * 16 + fq * 4;
    float sv[4][4];
#pragma unroll
    for (int sf = 0; sf < 4; ++sf) {
      int scol = s0 + sf * 16 + fr;
#pragma unroll
      for (int r = 0; r < 4; ++r) {
        float xv = sacc[sf][r];
        if (diag && scol > qrb + r) xv = -1e30f;
        sv[sf][r] = xv;
      }
    }
#pragma unroll
    for (int r = 0; r < 4; ++r) {
      float mx = fmaxf(fmaxf(sv[0][r], sv[1][r]), fmaxf(sv[2][r], sv[3][r]));
#pragma unroll
      for (int off = 1; off < 16; off <<= 1) mx = fmaxf(mx, __shfl_xor(mx, off, 16));
      float mnew = fmaxf(mrow[r], mx);
      float alpha = __expf(mrow[r] - mnew);
      float rs = 0.f;
#pragma unroll
      for (int sf = 0; sf < 4; ++sf) {
        float p = __expf(sv[sf][r] - mnew);
        Psh[wid][(fq * 4 + r) * 72 + sf * 16 + fr] = (__bf16)p;
        rs += p;
      }
#pragma unroll
      for (int off = 1; off < 16; off <<= 1) rs += __shfl_xor(rs, off, 16);
      lrow[r] = lrow[r] * alpha + rs;
      mrow[r] = mnew;
      oacc[0][r] *= alpha; oacc[1][r] *= alpha; oacc[2][r] *= alpha; oacc[3][r] *= alpha;
    }

    // O += P V   (A = P rows fr; B = VT cols d)
#pragma unroll
    for (int kk = 0; kk < 2; ++kk) {
      bf16x8 pf = *(const bf16x8*)&Psh[wid][fr * 72 + kk * 32 + fq * 8];
#pragma unroll
      for (int df = 0; df < 4; ++df) {
        bf16x8 vf = *(const bf16x8*)&VT[(df * 16 + fr) * 72 + kk * 32 + fq * 8];
        oacc[df] = __builtin_amdgcn_mfma_f32_16x16x32_bf16(pf, vf, oacc[df], 0, 0, 0);
      }
    }
    __syncthreads();
  }

#pragma unroll
  for (int r = 0; r < 4; ++r) {
    float inv = 1.0f / lrow[r];
    int t = q0 + wid * 16 + fq * 4 + r;
    size_t orow = ((size_t)b * 1024 + t) * 1024 + h * 64;
#pragma unroll
    for (int df = 0; df < 4; ++df)
      O[orow + df * 16 + fr] = (__bf16)(oacc[df][r] * inv);
  }
}

// ---------------------------------------------------------------- launch
extern "C" void kernel_launch(void* const* d_in, const int* in_sizes, int n_in,
                              void* d_out, int out_size, void* d_ws, size_t ws_size,
                              hipStream_t stream) {
  const float* x  = (const float*)d_in[0];
  const float* Wq = (const float*)d_in[1];
  const float* Wk = (const float*)d_in[2];
  const float* Wv = (const float*)d_in[3];
  const float* Wo = (const float*)d_in[4];
  const float* bo = (const float*)d_in[5];
  float* out = (float*)d_out;

  __bf16* xb    = (__bf16*)d_ws;                    // 4096x1024
  __bf16* wqkvT = xb + (size_t)4096 * 1024;         // 3072x1024
  __bf16* woT   = wqkvT + (size_t)3072 * 1024;      // 1024x1024
  __bf16* qb    = woT + (size_t)1024 * 1024;        // [B,H,T,D]
  __bf16* kb    = qb + (size_t)4 * 16 * 1024 * 64;
  __bf16* vb    = kb + (size_t)4 * 16 * 1024 * 64;
  __bf16* Ob    = vb + (size_t)4 * 16 * 1024 * 64;  // [B*T, H*D]

  // prep: cast x, transpose+cast weights into B^T layout
  cast_bf16_kernel<<<4096, 256, 0, stream>>>(x, xb, 4194304 / 4);
  transpose_cast_kernel<<<dim3(16, 1, 16), 256, 0, stream>>>(Wq, wqkvT, 64, 1024, 65536, 65536);
  transpose_cast_kernel<<<dim3(16, 1, 16), 256, 0, stream>>>(Wk, wqkvT + (size_t)1024 * 1024, 64, 1024, 65536, 65536);
  transpose_cast_kernel<<<dim3(16, 1, 16), 256, 0, stream>>>(Wv, wqkvT + (size_t)2048 * 1024, 64, 1024, 65536, 65536);
  transpose_cast_kernel<<<dim3(16, 16, 1), 256, 0, stream>>>(Wo, woT, 1024, 1024, 0, 0);

  // QKV projection: [4096,1024] @ [1024,3072]
  gemm_bt_kernel<0><<<dim3(32, 24), 256, 0, stream>>>(xb, wqkvT, 3072, qb, kb, vb, nullptr, nullptr);

  // causal flash attention
  attn_fwd_kernel<<<dim3(16, 64), 256, 0, stream>>>(qb, kb, vb, Ob);

  // output projection + bias: [4096,1024] @ [1024,1024]
  gemm_bt_kernel<1><<<dim3(32, 8), 256, 0, stream>>>(Ob, woT, 1024, nullptr, nullptr, nullptr, out, bo);
}

// Round 2
// 117.112 us; speedup vs baseline: 1.5831x; 1.5831x over previous
//
#include <hip/hip_runtime.h>
#include <hip/hip_bf16.h>
#include <stdint.h>

// B=4, T=1024, C=1024, H=16, D=64
// ws layout (bf16 elems): xb[4096*1024] | wqkvT[3072*1024] | woT[1024*1024]
//                       | q[4M] | k[4M] | vT[4M] | O[4M]

typedef float f32x4 __attribute__((ext_vector_type(4)));
typedef __bf16 bf16x8 __attribute__((ext_vector_type(8)));
typedef __bf16 bf16x4 __attribute__((ext_vector_type(4)));

#define GAS __attribute__((address_space(1)))
#define LAS __attribute__((address_space(3)))

// ---------------------------------------------------------------- cast x -> bf16
__global__ __launch_bounds__(256) void cast_bf16_kernel(
    const float* __restrict__ in, __bf16* __restrict__ out, int n4) {
  int i = blockIdx.x * 256 + threadIdx.x;
  if (i < n4) {
    float4 f = ((const float4*)in)[i];
    bf16x4 o;
    o[0] = (__bf16)f.x; o[1] = (__bf16)f.y; o[2] = (__bf16)f.z; o[3] = (__bf16)f.w;
    ((bf16x4*)out)[i] = o;
  }
}

// ------------------------------------------- transpose f32 [rows x cols] -> bf16 [cols x rows]
__global__ __launch_bounds__(256) void transpose_cast_kernel(
    const float* __restrict__ src, __bf16* __restrict__ dst,
    int src_ld, int dst_ld, long long src_mstride, long long dst_mstride) {
  __shared__ float tile[64][65];
  const float* s = src + (size_t)blockIdx.z * src_mstride;
  __bf16* d = dst + (size_t)blockIdx.z * dst_mstride;
  int r0 = blockIdx.x * 64, c0 = blockIdx.y * 64;
  int tx = threadIdx.x & 63, ty = threadIdx.x >> 6;
#pragma unroll
  for (int rr = ty; rr < 64; rr += 4)
    tile[rr][tx] = s[(size_t)(r0 + rr) * src_ld + (c0 + tx)];
  __syncthreads();
#pragma unroll
  for (int rr = ty; rr < 64; rr += 4)
    d[(size_t)(c0 + rr) * dst_ld + (r0 + tx)] = (__bf16)tile[tx][rr];
}

// ---------------------------------------------------------------- GEMM (A row-major, BT = B^T row-major)
// 128x128 tile, BK=32, 256 threads (4 waves 2x2, each 64x64), m97 structure.
// MODE 0: scatter-write q (pre-scaled 1/8), k as [B,H,T,D]; v TRANSPOSED as [B,H,D,T]
// MODE 1: fp32 out + bias
template <int MODE>
__global__ __launch_bounds__(256) void gemm_bt_kernel(
    const __bf16* __restrict__ A, const __bf16* __restrict__ BT, int N,
    __bf16* __restrict__ qo, __bf16* __restrict__ ko, __bf16* __restrict__ vo,
    float* __restrict__ Cout, const float* __restrict__ bias) {
  constexpr int K = 1024;
  __shared__ __align__(16) __bf16 Ash[128 * 32];
  __shared__ __align__(16) __bf16 Bsh[128 * 32];
  const int tid = threadIdx.x;
  const int wid = tid >> 6, lane = tid & 63;
  const int fr = lane & 15, fq = lane >> 4;
  const int m0 = blockIdx.x * 128, n0 = blockIdx.y * 128;
  const int wr = wid >> 1, wc = wid & 1;
  const int srow = lane >> 2, scol = (lane & 3) * 8;

  f32x4 acc[4][4] = {};

  for (int k0 = 0; k0 < K; k0 += 32) {
#pragma unroll
    for (int i = 0; i < 2; ++i) {
      int chunk = wid * 2 + i;          // 0..7, wave-uniform
      int row = chunk * 16 + srow;
      const __bf16* gA = A + (size_t)(m0 + row) * K + k0 + scol;
      const __bf16* gB = BT + (size_t)(n0 + row) * K + k0 + scol;
      __builtin_amdgcn_global_load_lds((const GAS void*)gA, (LAS void*)&Ash[chunk * 512], 16, 0, 0);
      __builtin_amdgcn_global_load_lds((const GAS void*)gB, (LAS void*)&Bsh[chunk * 512], 16, 0, 0);
    }
    __syncthreads();
    bf16x8 af[4], bfr[4];
#pragma unroll
    for (int mi = 0; mi < 4; ++mi)
      af[mi] = *(const bf16x8*)&Ash[(wr * 64 + mi * 16 + fr) * 32 + fq * 8];
#pragma unroll
    for (int ni = 0; ni < 4; ++ni)
      bfr[ni] = *(const bf16x8*)&Bsh[(wc * 64 + ni * 16 + fr) * 32 + fq * 8];
#pragma unroll
    for (int mi = 0; mi < 4; ++mi)
#pragma unroll
      for (int ni = 0; ni < 4; ++ni)
        acc[mi][ni] = __builtin_amdgcn_mfma_f32_16x16x32_bf16(af[mi], bfr[ni], acc[mi][ni], 0, 0, 0);
    __syncthreads();
  }

#pragma unroll
  for (int mi = 0; mi < 4; ++mi) {
#pragma unroll
    for (int ni = 0; ni < 4; ++ni) {
      int n = n0 + wc * 64 + ni * 16 + fr;
      int mb = m0 + wr * 64 + mi * 16 + fq * 4;
#pragma unroll
      for (int r = 0; r < 4; ++r) {
        int m = mb + r;
        float val = acc[mi][ni][r];
        if (MODE == 0) {
          int sec = n >> 10, nl = n & 1023;
          int h = nl >> 6, dd = nl & 63;
          int b = m >> 10, t = m & 1023;
          if (sec == 0) {
            qo[(((size_t)b * 16 + h) * 1024 + t) * 64 + dd] = (__bf16)(val * 0.125f);
          } else if (sec == 1) {
            ko[(((size_t)b * 16 + h) * 1024 + t) * 64 + dd] = (__bf16)val;
          } else {
            // V stored transposed: [B,H,D,T]
            vo[(((size_t)b * 16 + h) * 64 + dd) * 1024 + t] = (__bf16)val;
          }
        } else {
          Cout[(size_t)m * N + n] = val + bias[n];
        }
      }
    }
  }
}

// ---------------------------------------------------------------- flash attention (causal)
// grid (8, B*H); 256 threads = 4 waves. Block bx handles q-tiles {bx, 15-bx},
// sharing each staged K/V tile (balanced: 17 compute-units per block).
// K tile: [64 s][64 d] bf16, XOR-swizzled (chunk ^= row&7) via pre-swizzled
// global_load_lds source; VT tile: [64 d][64 s] from pre-transposed V, same swizzle.
// Swapped QK^T: S^T = mfma(K, Q) -> softmax row is lane-local (q = q0+wid*16+fr).
__global__ __launch_bounds__(256) void attn_fwd_kernel(
    const __bf16* __restrict__ Q, const __bf16* __restrict__ Kg,
    const __bf16* __restrict__ Vt, __bf16* __restrict__ O) {
  __shared__ __align__(16) __bf16 Ksh[2][64 * 64];
  __shared__ __align__(16) __bf16 VTs[2][64 * 64];
  __shared__ __align__(16) __bf16 Psh[4][16 * 72];

  const int bx = blockIdx.x, bh = blockIdx.y;
  const int b = bh >> 4, h = bh & 15;
  const size_t base = (size_t)bh * 1024 * 64;   // Q,K: [B,H,T,D]; Vt: [B,H,D,T] (same offset)
  const int tid = threadIdx.x, wid = tid >> 6, lane = tid & 63;
  const int fr = lane & 15, fq = lane >> 4;
  const int qta = bx, qtb = 15 - bx;            // qta < qtb always
  const int q0a = qta * 64, q0b = qtb * 64;

  // Q fragments (B-operand of swapped QK^T): Q[q0+wid*16+fr][fq*8..]
  bf16x8 qa[2], qbf[2];
  {
    int qra = q0a + wid * 16 + fr;
    qa[0] = *(const bf16x8*)&Q[base + (size_t)qra * 64 + fq * 8];
    qa[1] = *(const bf16x8*)&Q[base + (size_t)qra * 64 + 32 + fq * 8];
    int qrb = q0b + wid * 16 + fr;
    qbf[0] = *(const bf16x8*)&Q[base + (size_t)qrb * 64 + fq * 8];
    qbf[1] = *(const bf16x8*)&Q[base + (size_t)qrb * 64 + 32 + fq * 8];
  }
  f32x4 oa[4] = {}, ob[4] = {};
  float ma = -1e30f, la = 0.f, mb = -1e30f, lb = 0.f;  // state for q = q0x+wid*16+fr

  const int lrow8 = lane >> 3;        // 0..7: row-within-8 for staging
  const int lchunk = lane & 7;        // 16B chunk within 128B row
  const int schunk = lchunk ^ lrow8;  // pre-swizzled source chunk

  auto stage = [&](int st, int buf) {
    const int s0 = st * 64;
#pragma unroll
    for (int i = 0; i < 2; ++i) {
      int rowbase = i * 32 + wid * 8;             // wave-uniform
      int row = rowbase + lrow8;
      const __bf16* gK = Kg + base + (size_t)(s0 + row) * 64 + schunk * 8;
      __builtin_amdgcn_global_load_lds((const GAS void*)gK,
          (LAS void*)&Ksh[buf][rowbase * 64], 16, 0, 0);
      const __bf16* gV = Vt + base + (size_t)row * 1024 + s0 + schunk * 8;
      __builtin_amdgcn_global_load_lds((const GAS void*)gV,
          (LAS void*)&VTs[buf][rowbase * 64], 16, 0, 0);
    }
  };

  auto compute = [&](int buf, int s0, const bf16x8* qf, f32x4* oacc,
                     float& m, float& l, int q0x, bool maskT) {
    // S^T = K Q^T : D[s_local][q_local], lane holds s = sf*16+fq*4+r, q = fr
    f32x4 s[4];
    __builtin_amdgcn_s_setprio(1);
#pragma unroll
    for (int sf = 0; sf < 4; ++sf) {
      int row = sf * 16 + fr, rx = fr & 7;
      bf16x8 kf0 = *(const bf16x8*)&Ksh[buf][row * 64 + ((fq ^ rx) << 3)];
      f32x4 z = {};
      s[sf] = __builtin_amdgcn_mfma_f32_16x16x32_bf16(kf0, qf[0], z, 0, 0, 0);
      bf16x8 kf1 = *(const bf16x8*)&Ksh[buf][row * 64 + (((4 + fq) ^ rx) << 3)];
      s[sf] = __builtin_amdgcn_mfma_f32_16x16x32_bf16(kf1, qf[1], s[sf], 0, 0, 0);
    }
    __builtin_amdgcn_s_setprio(0);

    // online softmax, lane-local row q = q0x + wid*16 + fr
    const int qg = q0x + wid * 16 + fr;
    float sv[4][4];
    float mx = -1e30f;
#pragma unroll
    for (int sf = 0; sf < 4; ++sf)
#pragma unroll
      for (int r = 0; r < 4; ++r) {
        float x = s[sf][r];
        if (maskT) { int sg = s0 + sf * 16 + fq * 4 + r; if (sg > qg) x = -1e30f; }
        sv[sf][r] = x;
        mx = fmaxf(mx, x);
      }
    mx = fmaxf(mx, __shfl_xor(mx, 16));
    mx = fmaxf(mx, __shfl_xor(mx, 32));
    float mnew = fmaxf(m, mx);
    float alpha = __expf(m - mnew);
    m = mnew;
    float rs = 0.f;
#pragma unroll
    for (int sf = 0; sf < 4; ++sf) {
      bf16x4 pk;
#pragma unroll
      for (int r = 0; r < 4; ++r) {
        float p = __expf(sv[sf][r] - mnew);
        rs += p;
        pk[r] = (__bf16)p;
      }
      *(bf16x4*)&Psh[wid][fr * 72 + sf * 16 + fq * 4] = pk;  // P[q=fr][s]
    }
    rs += __shfl_xor(rs, 16);
    rs += __shfl_xor(rs, 32);
    l = l * alpha + rs;
    // broadcast alpha from lane (fr' = fq*4+r) to rescale oacc rows
    float ar[4];
#pragma unroll
    for (int r = 0; r < 4; ++r) ar[r] = __shfl(alpha, (lane & 48) | (fq * 4 + r));
#pragma unroll
    for (int df = 0; df < 4; ++df)
#pragma unroll
      for (int r = 0; r < 4; ++r) oacc[df][r] *= ar[r];

    // O += P V : A = P rows (q_local=fr), B = VT rows (d)
    __builtin_amdgcn_s_setprio(1);
#pragma unroll
    for (int kk = 0; kk < 2; ++kk) {
      bf16x8 pf = *(const bf16x8*)&Psh[wid][fr * 72 + kk * 32 + fq * 8];
#pragma unroll
      for (int df = 0; df < 4; ++df) {
        int row = df * 16 + fr;
        bf16x8 vf = *(const bf16x8*)&VTs[buf][row * 64 + ((((kk << 2) | fq) ^ (fr & 7)) << 3)];
        oacc[df] = __builtin_amdgcn_mfma_f32_16x16x32_bf16(pf, vf, oacc[df], 0, 0, 0);
      }
    }
    __builtin_amdgcn_s_setprio(0);
  };

  // pipeline: stage(st+1) issued before compute(st); one vmcnt(0)+barrier per tile
  stage(0, 0);
  __syncthreads();
  int cur = 0;
  for (int st = 0; st <= qtb; ++st) {
    if (st < qtb) stage(st + 1, cur ^ 1);
    compute(cur, st * 64, qbf, ob, mb, lb, q0b, st == qtb);
    if (st <= qta) compute(cur, st * 64, qa, oa, ma, la, q0a, st == qta);
    __syncthreads();
    cur ^= 1;
  }

  auto epilogue = [&](const f32x4* oacc, float l, int q0x) {
    float lr[4];
#pragma unroll
    for (int r = 0; r < 4; ++r) lr[r] = __shfl(l, (lane & 48) | (fq * 4 + r));
#pragma unroll
    for (int r = 0; r < 4; ++r) {
      float inv = 1.0f / lr[r];
      int t = q0x + wid * 16 + fq * 4 + r;
      size_t orow = ((size_t)b * 1024 + t) * 1024 + h * 64;
#pragma unroll
      for (int df = 0; df < 4; ++df)
        O[orow + df * 16 + fr] = (__bf16)(oacc[df][r] * inv);
    }
  };
  epilogue(ob, lb, q0b);
  epilogue(oa, la, q0a);
}

// ---------------------------------------------------------------- launch
extern "C" void kernel_launch(void* const* d_in, const int* in_sizes, int n_in,
                              void* d_out, int out_size, void* d_ws, size_t ws_size,
                              hipStream_t stream) {
  const float* x  = (const float*)d_in[0];
  const float* Wq = (const float*)d_in[1];
  const float* Wk = (const float*)d_in[2];
  const float* Wv = (const float*)d_in[3];
  const float* Wo = (const float*)d_in[4];
  const float* bo = (const float*)d_in[5];
  float* out = (float*)d_out;

  __bf16* xb    = (__bf16*)d_ws;                    // 4096x1024
  __bf16* wqkvT = xb + (size_t)4096 * 1024;         // 3072x1024
  __bf16* woT   = wqkvT + (size_t)3072 * 1024;      // 1024x1024
  __bf16* qb    = woT + (size_t)1024 * 1024;        // [B,H,T,D]
  __bf16* kb    = qb + (size_t)4 * 16 * 1024 * 64;  // [B,H,T,D]
  __bf16* vtb   = kb + (size_t)4 * 16 * 1024 * 64;  // [B,H,D,T]
  __bf16* Ob    = vtb + (size_t)4 * 16 * 1024 * 64; // [B*T, H*D]

  // prep: cast x, transpose+cast weights into B^T layout
  cast_bf16_kernel<<<4096, 256, 0, stream>>>(x, xb, 4194304 / 4);
  transpose_cast_kernel<<<dim3(16, 1, 16), 256, 0, stream>>>(Wq, wqkvT, 64, 1024, 65536, 65536);
  transpose_cast_kernel<<<dim3(16, 1, 16), 256, 0, stream>>>(Wk, wqkvT + (size_t)1024 * 1024, 64, 1024, 65536, 65536);
  transpose_cast_kernel<<<dim3(16, 1, 16), 256, 0, stream>>>(Wv, wqkvT + (size_t)2048 * 1024, 64, 1024, 65536, 65536);
  transpose_cast_kernel<<<dim3(16, 16, 1), 256, 0, stream>>>(Wo, woT, 1024, 1024, 0, 0);

  // QKV projection: [4096,1024] @ [1024,3072]
  gemm_bt_kernel<0><<<dim3(32, 24), 256, 0, stream>>>(xb, wqkvT, 3072, qb, kb, vtb, nullptr, nullptr);

  // causal flash attention (balanced paired q-tiles)
  attn_fwd_kernel<<<dim3(8, 64), 256, 0, stream>>>(qb, kb, vtb, Ob);

  // output projection + bias: [4096,1024] @ [1024,1024]
  gemm_bt_kernel<1><<<dim3(32, 8), 256, 0, stream>>>(Ob, woT, 1024, nullptr, nullptr, nullptr, out, bo);
}

// Round 3
// 115.344 us; speedup vs baseline: 1.6074x; 1.0153x over previous
//
#include <hip/hip_runtime.h>
#include <hip/hip_bf16.h>
#include <stdint.h>

// B=4, T=1024, C=1024, H=16, D=64
// ws layout (bf16 elems): xb[4096*1024] | wqkvT[3072*1024] | woT[1024*1024]
//                       | q[4M] | k[4M] | vT[4M] | O[4M]

typedef float f32x4 __attribute__((ext_vector_type(4)));
typedef __bf16 bf16x8 __attribute__((ext_vector_type(8)));
typedef __bf16 bf16x4 __attribute__((ext_vector_type(4)));

#define GAS __attribute__((address_space(1)))
#define LAS __attribute__((address_space(3)))

// ---------------------------------------------------------------- cast x -> bf16
__global__ __launch_bounds__(256) void cast_bf16_kernel(
    const float* __restrict__ in, __bf16* __restrict__ out, int n4) {
  int i = blockIdx.x * 256 + threadIdx.x;
  if (i < n4) {
    float4 f = ((const float4*)in)[i];
    bf16x4 o;
    o[0] = (__bf16)f.x; o[1] = (__bf16)f.y; o[2] = (__bf16)f.z; o[3] = (__bf16)f.w;
    ((bf16x4*)out)[i] = o;
  }
}

// ------------------------------------------- transpose f32 [rows x cols] -> bf16 [cols x rows]
__global__ __launch_bounds__(256) void transpose_cast_kernel(
    const float* __restrict__ src, __bf16* __restrict__ dst,
    int src_ld, int dst_ld, long long src_mstride, long long dst_mstride) {
  __shared__ float tile[64][65];
  const float* s = src + (size_t)blockIdx.z * src_mstride;
  __bf16* d = dst + (size_t)blockIdx.z * dst_mstride;
  int r0 = blockIdx.x * 64, c0 = blockIdx.y * 64;
  int tx = threadIdx.x & 63, ty = threadIdx.x >> 6;
#pragma unroll
  for (int rr = ty; rr < 64; rr += 4)
    tile[rr][tx] = s[(size_t)(r0 + rr) * src_ld + (c0 + tx)];
  __syncthreads();
#pragma unroll
  for (int rr = ty; rr < 64; rr += 4)
    d[(size_t)(c0 + rr) * dst_ld + (r0 + tx)] = (__bf16)tile[tx][rr];
}

// ---------------------------------------------------------------- GEMM (A row-major, BT = B^T row-major)
// 128x128 tile, BK=32, 256 threads (4 waves 2x2, each 64x64).
// 2-phase double-buffered global_load_lds staging (stage k+1 before compute k,
// ONE barrier per K-step) + XOR-swizzled LDS (chunk ^= (row>>1)&3, both sides)
// to cut the 8-way fragment-read bank conflict to free 2-way.
// MODE 0: scatter-write q (pre-scaled 1/8), k as [B,H,T,D]; v TRANSPOSED as [B,H,D,T]
// MODE 1: fp32 out + bias
template <int MODE>
__global__ __launch_bounds__(256) void gemm_bt_kernel(
    const __bf16* __restrict__ A, const __bf16* __restrict__ BT, int N,
    __bf16* __restrict__ qo, __bf16* __restrict__ ko, __bf16* __restrict__ vo,
    float* __restrict__ Cout, const float* __restrict__ bias) {
  constexpr int K = 1024;
  __shared__ __align__(16) __bf16 Ash[2][128 * 32];
  __shared__ __align__(16) __bf16 Bsh[2][128 * 32];
  const int tid = threadIdx.x;
  const int wid = tid >> 6, lane = tid & 63;
  const int fr = lane & 15, fq = lane >> 4;
  const int m0 = blockIdx.x * 128, n0 = blockIdx.y * 128;
  const int wr = wid >> 1, wc = wid & 1;
  const int srow = lane >> 2;
  // pre-swizzled source 16B-chunk: dest row_local = lane>>2, dest chunk = lane&3,
  // swizzle s(row) = (row>>1)&3 -> source chunk = (lane&3) ^ ((lane>>3)&3)
  const int scol = (((lane & 3) ^ ((lane >> 3) & 3))) * 8;
  // read-side swizzled chunk (uniform over mi/ni since 16-row steps are 0 mod 4 after >>1)
  const int swz = ((fq ^ ((fr >> 1) & 3))) << 3;

  f32x4 acc[4][4] = {};

  auto stage = [&](int k0, int buf) {
#pragma unroll
    for (int i = 0; i < 2; ++i) {
      int chunk = wid * 2 + i;          // 0..7, wave-uniform
      int row = chunk * 16 + srow;
      const __bf16* gA = A + (size_t)(m0 + row) * K + k0 + scol;
      const __bf16* gB = BT + (size_t)(n0 + row) * K + k0 + scol;
      __builtin_amdgcn_global_load_lds((const GAS void*)gA, (LAS void*)&Ash[buf][chunk * 512], 16, 0, 0);
      __builtin_amdgcn_global_load_lds((const GAS void*)gB, (LAS void*)&Bsh[buf][chunk * 512], 16, 0, 0);
    }
  };

  stage(0, 0);
  __syncthreads();
  int buf = 0;
  for (int k0 = 0; k0 < K; k0 += 32) {
    if (k0 + 32 < K) stage(k0 + 32, buf ^ 1);
    bf16x8 af[4], bfr[4];
#pragma unroll
    for (int mi = 0; mi < 4; ++mi) {
      int r = wr * 64 + mi * 16 + fr;
      af[mi] = *(const bf16x8*)&Ash[buf][r * 32 + swz];
    }
#pragma unroll
    for (int ni = 0; ni < 4; ++ni) {
      int r = wc * 64 + ni * 16 + fr;
      bfr[ni] = *(const bf16x8*)&Bsh[buf][r * 32 + swz];
    }
    __builtin_amdgcn_s_setprio(1);
#pragma unroll
    for (int mi = 0; mi < 4; ++mi)
#pragma unroll
      for (int ni = 0; ni < 4; ++ni)
        acc[mi][ni] = __builtin_amdgcn_mfma_f32_16x16x32_bf16(af[mi], bfr[ni], acc[mi][ni], 0, 0, 0);
    __builtin_amdgcn_s_setprio(0);
    __syncthreads();   // drains vmcnt (next stage) + lgkm; one barrier per K-step
    buf ^= 1;
  }

#pragma unroll
  for (int mi = 0; mi < 4; ++mi) {
#pragma unroll
    for (int ni = 0; ni < 4; ++ni) {
      int n = n0 + wc * 64 + ni * 16 + fr;
      int mb = m0 + wr * 64 + mi * 16 + fq * 4;
#pragma unroll
      for (int r = 0; r < 4; ++r) {
        int m = mb + r;
        float val = acc[mi][ni][r];
        if (MODE == 0) {
          int sec = n >> 10, nl = n & 1023;
          int h = nl >> 6, dd = nl & 63;
          int b = m >> 10, t = m & 1023;
          if (sec == 0) {
            qo[(((size_t)b * 16 + h) * 1024 + t) * 64 + dd] = (__bf16)(val * 0.125f);
          } else if (sec == 1) {
            ko[(((size_t)b * 16 + h) * 1024 + t) * 64 + dd] = (__bf16)val;
          } else {
            // V stored transposed: [B,H,D,T]
            vo[(((size_t)b * 16 + h) * 64 + dd) * 1024 + t] = (__bf16)val;
          }
        } else {
          Cout[(size_t)m * N + n] = val + bias[n];
        }
      }
    }
  }
}

// ---------------------------------------------------------------- flash attention (causal)
// grid (8, B*H); 256 threads = 4 waves. Block bx handles q-tiles {bx, 15-bx},
// sharing each staged K/V tile (balanced: 17 compute-units per block).
// K tile: [64 s][64 d] bf16, XOR-swizzled (chunk ^= row&7) via pre-swizzled
// global_load_lds source; VT tile: [64 d][64 s] from pre-transposed V, same swizzle.
// Swapped QK^T: S^T = mfma(K, Q) -> softmax row is lane-local (q = q0+wid*16+fr).
__global__ __launch_bounds__(256) void attn_fwd_kernel(
    const __bf16* __restrict__ Q, const __bf16* __restrict__ Kg,
    const __bf16* __restrict__ Vt, __bf16* __restrict__ O) {
  __shared__ __align__(16) __bf16 Ksh[2][64 * 64];
  __shared__ __align__(16) __bf16 VTs[2][64 * 64];
  __shared__ __align__(16) __bf16 Psh[4][16 * 72];

  const int bx = blockIdx.x, bh = blockIdx.y;
  const int b = bh >> 4, h = bh & 15;
  const size_t base = (size_t)bh * 1024 * 64;   // Q,K: [B,H,T,D]; Vt: [B,H,D,T] (same offset)
  const int tid = threadIdx.x, wid = tid >> 6, lane = tid & 63;
  const int fr = lane & 15, fq = lane >> 4;
  const int qta = bx, qtb = 15 - bx;            // qta < qtb always
  const int q0a = qta * 64, q0b = qtb * 64;

  // Q fragments (B-operand of swapped QK^T): Q[q0+wid*16+fr][fq*8..]
  bf16x8 qa[2], qbf[2];
  {
    int qra = q0a + wid * 16 + fr;
    qa[0] = *(const bf16x8*)&Q[base + (size_t)qra * 64 + fq * 8];
    qa[1] = *(const bf16x8*)&Q[base + (size_t)qra * 64 + 32 + fq * 8];
    int qrb = q0b + wid * 16 + fr;
    qbf[0] = *(const bf16x8*)&Q[base + (size_t)qrb * 64 + fq * 8];
    qbf[1] = *(const bf16x8*)&Q[base + (size_t)qrb * 64 + 32 + fq * 8];
  }
  f32x4 oa[4] = {}, ob[4] = {};
  float ma = -1e30f, la = 0.f, mb = -1e30f, lb = 0.f;  // state for q = q0x+wid*16+fr

  const int lrow8 = lane >> 3;        // 0..7: row-within-8 for staging
  const int lchunk = lane & 7;        // 16B chunk within 128B row
  const int schunk = lchunk ^ lrow8;  // pre-swizzled source chunk

  auto stage = [&](int st, int buf) {
    const int s0 = st * 64;
#pragma unroll
    for (int i = 0; i < 2; ++i) {
      int rowbase = i * 32 + wid * 8;             // wave-uniform
      int row = rowbase + lrow8;
      const __bf16* gK = Kg + base + (size_t)(s0 + row) * 64 + schunk * 8;
      __builtin_amdgcn_global_load_lds((const GAS void*)gK,
          (LAS void*)&Ksh[buf][rowbase * 64], 16, 0, 0);
      const __bf16* gV = Vt + base + (size_t)row * 1024 + s0 + schunk * 8;
      __builtin_amdgcn_global_load_lds((const GAS void*)gV,
          (LAS void*)&VTs[buf][rowbase * 64], 16, 0, 0);
    }
  };

  auto compute = [&](int buf, int s0, const bf16x8* qf, f32x4* oacc,
                     float& m, float& l, int q0x, bool maskT) {
    // S^T = K Q^T : D[s_local][q_local], lane holds s = sf*16+fq*4+r, q = fr
    f32x4 s[4];
    __builtin_amdgcn_s_setprio(1);
#pragma unroll
    for (int sf = 0; sf < 4; ++sf) {
      int row = sf * 16 + fr, rx = fr & 7;
      bf16x8 kf0 = *(const bf16x8*)&Ksh[buf][row * 64 + ((fq ^ rx) << 3)];
      f32x4 z = {};
      s[sf] = __builtin_amdgcn_mfma_f32_16x16x32_bf16(kf0, qf[0], z, 0, 0, 0);
      bf16x8 kf1 = *(const bf16x8*)&Ksh[buf][row * 64 + (((4 + fq) ^ rx) << 3)];
      s[sf] = __builtin_amdgcn_mfma_f32_16x16x32_bf16(kf1, qf[1], s[sf], 0, 0, 0);
    }
    __builtin_amdgcn_s_setprio(0);

    // online softmax, lane-local row q = q0x + wid*16 + fr
    const int qg = q0x + wid * 16 + fr;
    float sv[4][4];
    float mx = -1e30f;
#pragma unroll
    for (int sf = 0; sf < 4; ++sf)
#pragma unroll
      for (int r = 0; r < 4; ++r) {
        float x = s[sf][r];
        if (maskT) { int sg = s0 + sf * 16 + fq * 4 + r; if (sg > qg) x = -1e30f; }
        sv[sf][r] = x;
        mx = fmaxf(mx, x);
      }
    mx = fmaxf(mx, __shfl_xor(mx, 16));
    mx = fmaxf(mx, __shfl_xor(mx, 32));
    float mnew = fmaxf(m, mx);
    float alpha = __expf(m - mnew);
    m = mnew;
    float rs = 0.f;
#pragma unroll
    for (int sf = 0; sf < 4; ++sf) {
      bf16x4 pk;
#pragma unroll
      for (int r = 0; r < 4; ++r) {
        float p = __expf(sv[sf][r] - mnew);
        rs += p;
        pk[r] = (__bf16)p;
      }
      *(bf16x4*)&Psh[wid][fr * 72 + sf * 16 + fq * 4] = pk;  // P[q=fr][s]
    }
    rs += __shfl_xor(rs, 16);
    rs += __shfl_xor(rs, 32);
    l = l * alpha + rs;
    // broadcast alpha from lane (fr' = fq*4+r) to rescale oacc rows
    float ar[4];
#pragma unroll
    for (int r = 0; r < 4; ++r) ar[r] = __shfl(alpha, (lane & 48) | (fq * 4 + r));
#pragma unroll
    for (int df = 0; df < 4; ++df)
#pragma unroll
      for (int r = 0; r < 4; ++r) oacc[df][r] *= ar[r];

    // O += P V : A = P rows (q_local=fr), B = VT rows (d)
    __builtin_amdgcn_s_setprio(1);
#pragma unroll
    for (int kk = 0; kk < 2; ++kk) {
      bf16x8 pf = *(const bf16x8*)&Psh[wid][fr * 72 + kk * 32 + fq * 8];
#pragma unroll
      for (int df = 0; df < 4; ++df) {
        int row = df * 16 + fr;
        bf16x8 vf = *(const bf16x8*)&VTs[buf][row * 64 + ((((kk << 2) | fq) ^ (fr & 7)) << 3)];
        oacc[df] = __builtin_amdgcn_mfma_f32_16x16x32_bf16(pf, vf, oacc[df], 0, 0, 0);
      }
    }
    __builtin_amdgcn_s_setprio(0);
  };

  // pipeline: stage(st+1) issued before compute(st); one vmcnt(0)+barrier per tile
  stage(0, 0);
  __syncthreads();
  int cur = 0;
  for (int st = 0; st <= qtb; ++st) {
    if (st < qtb) stage(st + 1, cur ^ 1);
    compute(cur, st * 64, qbf, ob, mb, lb, q0b, st == qtb);
    if (st <= qta) compute(cur, st * 64, qa, oa, ma, la, q0a, st == qta);
    __syncthreads();
    cur ^= 1;
  }

  auto epilogue = [&](const f32x4* oacc, float l, int q0x) {
    float lr[4];
#pragma unroll
    for (int r = 0; r < 4; ++r) lr[r] = __shfl(l, (lane & 48) | (fq * 4 + r));
#pragma unroll
    for (int r = 0; r < 4; ++r) {
      float inv = 1.0f / lr[r];
      int t = q0x + wid * 16 + fq * 4 + r;
      size_t orow = ((size_t)b * 1024 + t) * 1024 + h * 64;
#pragma unroll
      for (int df = 0; df < 4; ++df)
        O[orow + df * 16 + fr] = (__bf16)(oacc[df][r] * inv);
    }
  };
  epilogue(ob, lb, q0b);
  epilogue(oa, la, q0a);
}

// ---------------------------------------------------------------- launch
extern "C" void kernel_launch(void* const* d_in, const int* in_sizes, int n_in,
                              void* d_out, int out_size, void* d_ws, size_t ws_size,
                              hipStream_t stream) {
  const float* x  = (const float*)d_in[0];
  const float* Wq = (const float*)d_in[1];
  const float* Wk = (const float*)d_in[2];
  const float* Wv = (const float*)d_in[3];
  const float* Wo = (const float*)d_in[4];
  const float* bo = (const float*)d_in[5];
  float* out = (float*)d_out;

  __bf16* xb    = (__bf16*)d_ws;                    // 4096x1024
  __bf16* wqkvT = xb + (size_t)4096 * 1024;         // 3072x1024
  __bf16* woT   = wqkvT + (size_t)3072 * 1024;      // 1024x1024
  __bf16* qb    = woT + (size_t)1024 * 1024;        // [B,H,T,D]
  __bf16* kb    = qb + (size_t)4 * 16 * 1024 * 64;  // [B,H,T,D]
  __bf16* vtb   = kb + (size_t)4 * 16 * 1024 * 64;  // [B,H,D,T]
  __bf16* Ob    = vtb + (size_t)4 * 16 * 1024 * 64; // [B*T, H*D]

  // prep: cast x, transpose+cast weights into B^T layout
  cast_bf16_kernel<<<4096, 256, 0, stream>>>(x, xb, 4194304 / 4);
  transpose_cast_kernel<<<dim3(16, 1, 16), 256, 0, stream>>>(Wq, wqkvT, 64, 1024, 65536, 65536);
  transpose_cast_kernel<<<dim3(16, 1, 16), 256, 0, stream>>>(Wk, wqkvT + (size_t)1024 * 1024, 64, 1024, 65536, 65536);
  transpose_cast_kernel<<<dim3(16, 1, 16), 256, 0, stream>>>(Wv, wqkvT + (size_t)2048 * 1024, 64, 1024, 65536, 65536);
  transpose_cast_kernel<<<dim3(16, 16, 1), 256, 0, stream>>>(Wo, woT, 1024, 1024, 0, 0);

  // QKV projection: [4096,1024] @ [1024,3072]
  gemm_bt_kernel<0><<<dim3(32, 24), 256, 0, stream>>>(xb, wqkvT, 3072, qb, kb, vtb, nullptr, nullptr);

  // causal flash attention (balanced paired q-tiles)
  attn_fwd_kernel<<<dim3(8, 64), 256, 0, stream>>>(qb, kb, vtb, Ob);

  // output projection + bias: [4096,1024] @ [1024,1024]
  gemm_bt_kernel<1><<<dim3(32, 8), 256, 0, stream>>>(Ob, woT, 1024, nullptr, nullptr, nullptr, out, bo);
}